// Round 4
// baseline (8016.240 us; speedup 1.0000x reference)
//
#include <hip/hip_runtime.h>
#include <hip/hip_bf16.h>

#define NB    128
#define LSEQ  512
#define HIDN  512
#define EMB   256
#define DTOT  768
#define GRID_MAIN 32    // cooperative blocks; block wg owns hidden units [wg*16, wg*16+16)

typedef __attribute__((ext_vector_type(8))) short  short8;   // MFMA A/B frag (8 bf16)
typedef __attribute__((ext_vector_type(4))) float  floatx4;  // MFMA C/D frag
typedef __attribute__((ext_vector_type(4))) unsigned int uintx4;

__device__ __forceinline__ unsigned short f2bf(float f) {   // RNE
  unsigned u = __builtin_bit_cast(unsigned, f);
  unsigned r = u + 0x7fffu + ((u >> 16) & 1u);
  return (unsigned short)(r >> 16);
}
__device__ __forceinline__ unsigned bfpair(float lo, float hi) {
  unsigned a = __builtin_bit_cast(unsigned, lo) + 0x8000u;
  unsigned b = __builtin_bit_cast(unsigned, hi) + 0x8000u;
  return __builtin_amdgcn_perm(b, a, 0x07060302u);
}
__device__ __forceinline__ short8 pack8(float4 u, float4 v) {
  union { short8 s; uintx4 w; } cv;
  cv.w[0] = bfpair(u.x, u.y); cv.w[1] = bfpair(u.z, u.w);
  cv.w[2] = bfpair(v.x, v.y); cv.w[3] = bfpair(v.z, v.w);
  return cv.s;
}
__device__ __forceinline__ float sigmoid_f(float x) { return 1.f / (1.f + __expf(-x)); }
__device__ __forceinline__ float tanh_f(float x) {
  float e = __expf(2.f * x);
  return 1.f - 2.f / (e + 1.f);
}

// agent-scope coherent 16B pull (2x 8B atomic loads — served at the L3
// coherence point; bypasses the stale per-XCD L2s)
__device__ __forceinline__ short8 pull16(const unsigned long long* p) {
  union { unsigned long long u[2]; short8 s; } r;
  r.u[0] = __hip_atomic_load(p,     __ATOMIC_RELAXED, __HIP_MEMORY_SCOPE_AGENT);
  r.u[1] = __hip_atomic_load(p + 1, __ATOMIC_RELAXED, __HIP_MEMORY_SCOPE_AGENT);
  return r.s;
}

// xe[t][n][e] = bf16(E[X[n][t]][e]) — time-major, k-contiguous
__global__ void prep_x_kernel(const int* __restrict__ X, const float* __restrict__ E,
                              unsigned short* __restrict__ xe) {
  int t = blockIdx.x, n = blockIdx.y;
  int row = X[(size_t)n * LSEQ + t];
  float4 v = ((const float4*)(E + (size_t)row * EMB))[threadIdx.x];
  ushort4 o;
  o.x = f2bf(v.x); o.y = f2bf(v.y); o.z = f2bf(v.z); o.w = f2bf(v.w);
  *(ushort4*)(xe + ((size_t)t * NB + n) * EMB + threadIdx.x * 4) = o;
}

// ---- main cooperative recurrence kernel ----------------------------------
// 32 blocks x 64 gate-cols: h broadcast = 32 x 128KB = 4MB/step (was 16MB).
// LDS capped at 64KB: cooperative launch validates against sharedMemPerBlock
// (65536) — the 128KB tile was why R2/R3 launches failed. h is staged in TWO
// 64-row halves through one 64KB buffer; row-tile q<4 needs only rows 0..63
// and q>=4 only rows 64..127, so each half fully completes 4 acc chains.
// Both halves are pulled to registers up front (32 coherent 16B loads, one
// L3 round-trip); writes are XOR-swizzled, reads are ds_read_b128 at the
// structural bank minimum.
template <bool USE_XE>
__global__ void __launch_bounds__(256, 1)
lstm_main(const int* __restrict__ X, const float* __restrict__ E,
          const unsigned short* __restrict__ xe,
          const float* __restrict__ Wi, const float* __restrict__ bi,
          const float* __restrict__ Wf, const float* __restrict__ bf_,
          const float* __restrict__ Wo, const float* __restrict__ bo,
          const float* __restrict__ Wh, const float* __restrict__ bh,
          float* __restrict__ out, unsigned short* __restrict__ hb,
          int* __restrict__ arrive) {
  __shared__ __align__(16) char smem[65536];     // 64-row half-tile of h
  const int wg   = blockIdx.x;
  const int tid  = threadIdx.x;
  const int lane = tid & 63;
  const int wv   = tid >> 6;
  const int l15  = lane & 15;
  const int l4   = lane >> 4;

  // --- W fragments (A operand): wave wv owns gate-cols wg*64+wv*16 .. +16 ---
  const int cg = wg * 64 + wv * 16 + l15;    // gate column c = j*4+g
  const int jcol = cg >> 2, g = cg & 3;
  const float* Wg = (g == 0) ? Wi : (g == 1) ? Wf : (g == 2) ? Wo : Wh;
  short8 bfrag[24];
#pragma unroll
  for (int kt = 0; kt < 24; ++kt) {
    union { short8 s; unsigned short us[8]; } cv;
#pragma unroll
    for (int e = 0; e < 8; ++e) {
      int k = kt * 32 + l4 * 8 + e;
      cv.us[e] = f2bf(Wg[(size_t)k * HIDN + jcol]);
    }
    bfrag[kt] = cv.s;
  }

  const int jglob = wg * 16 + wv * 4 + l4;   // hidden unit this lane's D-col maps to
  const float bI = bi[jglob], bF = bf_[jglob], bO = bo[jglob], bH = bh[jglob];
  float c[8];
#pragma unroll
  for (int q = 0; q < 8; ++q) c[q] = 0.f;

  unsigned short* hcur = hb;                       // zeroed by host memset: h_0 = 0
  unsigned short* hnxt = hb + (size_t)NB * HIDN;

  // --- acc starts with the x-GEMM contribution for step 0 (8 row-tiles) ---
  floatx4 acc[8];
#pragma unroll
  for (int q = 0; q < 8; ++q) {
    int n = q * 16 + l15;
    short8 xq[8];
    if (USE_XE) {
      const unsigned short* xr = xe + (size_t)n * EMB + l4 * 8;
#pragma unroll
      for (int kt = 0; kt < 8; ++kt) xq[kt] = *(const short8*)(xr + kt * 32);
    } else {
      int idx = X[(size_t)n * LSEQ + 0];
      const float* er = E + (size_t)idx * EMB + l4 * 8;
#pragma unroll
      for (int kt = 0; kt < 8; ++kt) {
        float4 u = *(const float4*)(er + kt * 32);
        float4 v = *(const float4*)(er + kt * 32 + 4);
        xq[kt] = pack8(u, v);
      }
    }
    acc[q] = floatx4{0.f, 0.f, 0.f, 0.f};
#pragma unroll
    for (int kt = 0; kt < 8; ++kt)
      acc[q] = __builtin_amdgcn_mfma_f32_16x16x32_bf16(bfrag[16 + kt], xq[kt], acc[q], 0, 0, 0);
  }

  const int swz = (l15 & 7) << 4;            // read-side swizzle: (global row)&7 == l15&7

  for (int t = 0; t < LSEQ; ++t) {
    // --- pull BOTH h halves into registers: wave wv owns rows
    //     {wv*16+cc} (half 0) and {64+wv*16+cc} (half 1), cc in [0,16).
    //     All 32 coherent 16B loads issued back-to-back -> one round-trip.
    short8 p1[16], p2[16];
#pragma unroll
    for (int cc = 0; cc < 16; ++cc) {
      int r1 = wv * 16 + cc;
      p1[cc] = pull16((const unsigned long long*)hcur + (size_t)r1 * 128 + lane * 2);
    }
#pragma unroll
    for (int cc = 0; cc < 16; ++cc) {
      int r2 = 64 + wv * 16 + cc;
      p2[cc] = pull16((const unsigned long long*)hcur + (size_t)r2 * 128 + lane * 2);
    }

    // --- half 0: write rows [0,64), compute q = 0..3 ---
#pragma unroll
    for (int cc = 0; cc < 16; ++cc) {
      int row = wv * 16 + cc;                // LDS row == global row (<64)
      *(short8*)(smem + (((size_t)row * 1024 + lane * 16) ^ ((cc & 7) << 4))) = p1[cc];
    }
    __syncthreads();                         // A: half-0 staged

#pragma unroll
    for (int half = 0; half < 2; ++half) {
      if (half == 1) {
        __syncthreads();                     // B: half-0 reads done
#pragma unroll
        for (int cc = 0; cc < 16; ++cc) {
          int row = wv * 16 + cc;            // LDS row == global row - 64; same key mod 8
          *(short8*)(smem + (((size_t)row * 1024 + lane * 16) ^ ((cc & 7) << 4))) = p2[cc];
        }
        __syncthreads();                     // C: half-1 staged
      }
      const int qlo = half * 4;
#pragma unroll
      for (int kt = 0; kt < 16; ++kt) {
        short8 hq[4];
#pragma unroll
        for (int qq = 0; qq < 4; ++qq) {
          int nl = qq * 16 + l15;            // LDS row
          hq[qq] = *(const short8*)(smem + (((size_t)nl * 1024 + kt * 64 + l4 * 16) ^ swz));
        }
#pragma unroll
        for (int qq = 0; qq < 4; ++qq)
          acc[qlo + qq] = __builtin_amdgcn_mfma_f32_16x16x32_bf16(bfrag[kt], hq[qq],
                                                                  acc[qlo + qq], 0, 0, 0);
      }

      // --- gates + h store for q = qlo..qlo+3 ---
#pragma unroll
      for (int qq = 0; qq < 4; ++qq) {
        int q = qlo + qq;
        floatx4 z = acc[q];
        float ig = sigmoid_f(z[0] + bI);
        float fg = sigmoid_f(z[1] + bF);
        float og = sigmoid_f(z[2] + bO);
        float gg = tanh_f(z[3] + bH);
        c[q] = fg * c[q] + ig * gg;
        float hv = og * tanh_f(c[q]);

        unsigned w  = (unsigned)f2bf(hv);
        unsigned wp = (unsigned)__builtin_amdgcn_ds_swizzle((int)w, 0x401F); // xor 16
        if ((l4 & 1) == 0) {
          unsigned val = w | (wp << 16);
          unsigned* p = (unsigned*)(hnxt + (size_t)(q * 16 + l15) * HIDN + jglob);
          __hip_atomic_store(p, val, __ATOMIC_RELAXED, __HIP_MEMORY_SCOPE_AGENT);
        }
        if (t == LSEQ - 1)
          out[(size_t)(q * 16 + l15) * HIDN + jglob] = hv;
      }
    }

    if (t == LSEQ - 1) break;

    { unsigned short* tmp = hcur; hcur = hnxt; hnxt = tmp; }

    const int gen = t + 1;
    // D: drains the 8 h stores (vmcnt(0)) + orders this step's LDS reads
    // before next step's ds_writes.
    __syncthreads();
    if (tid == 0)
      __hip_atomic_store(&arrive[wg], gen, __ATOMIC_RELAXED,
                         __HIP_MEMORY_SCOPE_AGENT);

    // --- off-chain: x-GEMM for t+1 while other blocks arrive ---
#pragma unroll
    for (int q = 0; q < 8; ++q) {
      int n = q * 16 + l15;
      short8 xq[8];
      if (USE_XE) {
        const unsigned short* xr = xe + ((size_t)(t + 1) * NB + n) * EMB + l4 * 8;
#pragma unroll
        for (int kt = 0; kt < 8; ++kt) xq[kt] = *(const short8*)(xr + kt * 32);
      } else {
        int idx = X[(size_t)n * LSEQ + t + 1];
        const float* er = E + (size_t)idx * EMB + l4 * 8;
#pragma unroll
        for (int kt = 0; kt < 8; ++kt) {
          float4 u = *(const float4*)(er + kt * 32);
          float4 v = *(const float4*)(er + kt * 32 + 4);
          xq[kt] = pack8(u, v);
        }
      }
      acc[q] = floatx4{0.f, 0.f, 0.f, 0.f};
#pragma unroll
      for (int kt = 0; kt < 8; ++kt)
        acc[q] = __builtin_amdgcn_mfma_f32_16x16x32_bf16(bfrag[16 + kt], xq[kt], acc[q], 0, 0, 0);
    }

    // --- poll: 32 packed flags (one cache line); lane spins on flag lane&31
    {
      const int* sp = &arrive[lane & 31];
      int va;
      do {
        va = __hip_atomic_load(sp, __ATOMIC_RELAXED, __HIP_MEMORY_SCOPE_AGENT);
      } while (va < gen);
    }
    __atomic_signal_fence(__ATOMIC_ACQUIRE);  // compiler barrier only
  }
}

// ws layout: [0, 8192) arrival slots (packed 4B stride; 128B used), [8192,
// +262144) h double buffer, then (optional, if ws_size permits) xe bf16
// time-major (33.5 MB).
extern "C" void kernel_launch(void* const* d_in, const int* in_sizes, int n_in,
                              void* d_out, int out_size, void* d_ws, size_t ws_size,
                              hipStream_t stream) {
  const int*   X  = (const int*)d_in[0];
  const float* E  = (const float*)d_in[1];
  const float* Wi = (const float*)d_in[2];
  const float* bi = (const float*)d_in[3];
  const float* Wf = (const float*)d_in[4];
  const float* bf = (const float*)d_in[5];
  const float* Wo = (const float*)d_in[6];
  const float* bo = (const float*)d_in[7];
  const float* Wh = (const float*)d_in[8];
  const float* bh = (const float*)d_in[9];
  float* out = (float*)d_out;

  char* ws = (char*)d_ws;
  int* arrive = (int*)ws;
  unsigned short* hb = (unsigned short*)(ws + 8192);
  const size_t xe_off = 8192 + 2 * (size_t)NB * HIDN * sizeof(unsigned short);
  const size_t xe_bytes = (size_t)LSEQ * NB * EMB * sizeof(unsigned short);
  const bool use_xe = ws_size >= xe_off + xe_bytes;
  unsigned short* xe = use_xe ? (unsigned short*)(ws + xe_off) : nullptr;

  hipMemsetAsync(ws, 0, xe_off, stream);  // zero barrier slots + h_0

  if (use_xe)
    prep_x_kernel<<<dim3(LSEQ, NB), dim3(64), 0, stream>>>(X, E, xe);

  void* args[] = { (void*)&X, (void*)&E, (void*)&xe,
                   (void*)&Wi, (void*)&bi, (void*)&Wf, (void*)&bf,
                   (void*)&Wo, (void*)&bo, (void*)&Wh, (void*)&bh,
                   (void*)&out, (void*)&hb, (void*)&arrive };
  hipError_t lerr;
  if (use_xe)
    lerr = hipLaunchCooperativeKernel(reinterpret_cast<void*>(lstm_main<true>),
                                      dim3(GRID_MAIN), dim3(256), args, 0, stream);
  else
    lerr = hipLaunchCooperativeKernel(reinterpret_cast<void*>(lstm_main<false>),
                                      dim3(GRID_MAIN), dim3(256), args, 0, stream);
  if (lerr != hipSuccess) {
    // fallback: plain launch — 32 blocks at 1/CU on a 256-CU device are
    // trivially co-resident; the barrier is hand-rolled atomics (no grid-sync
    // API used), so cooperative-launch semantics are not required.
    if (use_xe)
      lstm_main<true><<<dim3(GRID_MAIN), dim3(256), 0, stream>>>(
          X, E, xe, Wi, bi, Wf, bf, Wo, bo, Wh, bh, out, hb, arrive);
    else
      lstm_main<false><<<dim3(GRID_MAIN), dim3(256), 0, stream>>>(
          X, E, xe, Wi, bi, Wf, bf, Wo, bo, Wh, bh, out, hb, arrive);
  }
}

// Round 5
// 5582.807 us; speedup vs baseline: 1.4359x; 1.4359x over previous
//
#include <hip/hip_runtime.h>
#include <hip/hip_bf16.h>

#define NB    128
#define LSEQ  512
#define HIDN  512
#define EMB   256
#define GRID_ALL 256    // one block per CU (forced by 128KB LDS); 32/XCD
#define TEAM  32        // elected blocks, all on ONE XCD; rank r owns cols [r*64, r*64+64)

typedef __attribute__((ext_vector_type(8))) short  short8;   // MFMA A/B frag (8 bf16)
typedef __attribute__((ext_vector_type(4))) float  floatx4;  // MFMA C/D frag
typedef __attribute__((ext_vector_type(4))) unsigned int uintx4;

__device__ __forceinline__ unsigned short f2bf(float f) {   // RNE
  unsigned u = __builtin_bit_cast(unsigned, f);
  unsigned r = u + 0x7fffu + ((u >> 16) & 1u);
  return (unsigned short)(r >> 16);
}
__device__ __forceinline__ unsigned bfpair(float lo, float hi) {
  unsigned a = __builtin_bit_cast(unsigned, lo) + 0x8000u;
  unsigned b = __builtin_bit_cast(unsigned, hi) + 0x8000u;
  return __builtin_amdgcn_perm(b, a, 0x07060302u);
}
__device__ __forceinline__ short8 pack8(float4 u, float4 v) {
  union { short8 s; uintx4 w; } cv;
  cv.w[0] = bfpair(u.x, u.y); cv.w[1] = bfpair(u.z, u.w);
  cv.w[2] = bfpair(v.x, v.y); cv.w[3] = bfpair(v.z, v.w);
  return cv.s;
}
__device__ __forceinline__ float sigmoid_f(float x) { return 1.f / (1.f + __expf(-x)); }
__device__ __forceinline__ float tanh_f(float x) {
  float e = __expf(2.f * x);
  return 1.f - 2.f / (e + 1.f);
}

// sc0 load: bypass L1 ONLY -> served by the XCD-local L2 (~250cy), which is
// the coherence point for CUs on the same XCD (CDNA L1 is write-through, so
// peer plain-stores are already committed there after their vmcnt drain).
// This replaces the agent-scope (sc0 sc1) path that went all the way to L3.
__device__ __forceinline__ short8 ld16_sc0(const void* p) {
  short8 d;
  asm volatile("global_load_dwordx4 %0, %1, off sc0"
               : "=v"(d) : "v"(p) : "memory");
  return d;
}
__device__ __forceinline__ int ld_flag_sc0(const int* p) {
  int v;
  asm volatile("global_load_dword %0, %1, off sc0\n\t"
               "s_waitcnt vmcnt(0)"
               : "=v"(v) : "v"(p) : "memory");
  return v;
}

// xe[t][n][e] = bf16(E[X[n][t]][e]) — time-major, k-contiguous
__global__ void prep_x_kernel(const int* __restrict__ X, const float* __restrict__ E,
                              unsigned short* __restrict__ xe) {
  int t = blockIdx.x, n = blockIdx.y;
  int row = X[(size_t)n * LSEQ + t];
  float4 v = ((const float4*)(E + (size_t)row * EMB))[threadIdx.x];
  ushort4 o;
  o.x = f2bf(v.x); o.y = f2bf(v.y); o.z = f2bf(v.z); o.w = f2bf(v.w);
  *(ushort4*)(xe + ((size_t)t * NB + n) * EMB + threadIdx.x * 4) = o;
}

// ---- main recurrence kernel: single-XCD team --------------------------------
// R4 proved the bottleneck is the LATENCY of the agent-coherent (L3) path,
// not fabric volume. Fix: elect 32 co-resident blocks on ONE XCD (per-XCD
// ticket + first-to-fill-wins CAS); all h/flag exchange then stays in that
// XCD's L2: plain stores (write-through L1, vmcnt-drained) + sc0 loads.
// Compute shape: rank owns 64 gate-cols; wave = 32 cols x 64 rows (halves
// LDS read amplification vs R4); full 128-row h tile in 128KB static LDS;
// 2 barriers/step. Plain launch (cooperative launch rejects >64KB LDS).
template <bool USE_XE>
__global__ void __launch_bounds__(256, 1)
lstm_main(const int* __restrict__ X, const float* __restrict__ E,
          const unsigned short* __restrict__ xe,
          const float* __restrict__ Wi, const float* __restrict__ bi,
          const float* __restrict__ Wf, const float* __restrict__ bf_,
          const float* __restrict__ Wo, const float* __restrict__ bo,
          const float* __restrict__ Wh, const float* __restrict__ bh,
          float* __restrict__ out, unsigned short* __restrict__ hb,
          int* __restrict__ ctrl) {
  __shared__ __align__(16) char smem[131072];   // full 128-row h tile (forces 1 block/CU)
  __shared__ int s_rank;

  int* arrive = ctrl;          // ints [0,32): per-rank step flags
  int* ticket = ctrl + 64;     // ints [64,72): per-XCD ticket counters
  int* winner = ctrl + 128;    // int 128: winning xcd + 1 (0 = undecided)

  const int tid  = threadIdx.x;
  const int lane = tid & 63;
  const int wv   = tid >> 6;
  const int l15  = lane & 15;
  const int l4   = lane >> 4;

  // ---- election: first XCD to fill TEAM resident blocks wins ----
  int xcc;
  asm volatile("s_getreg_b32 %0, hwreg(HW_REG_XCC_ID)" : "=s"(xcc));
  if (tid == 0) {
    int r = __hip_atomic_fetch_add(&ticket[xcc], 1, __ATOMIC_RELAXED,
                                   __HIP_MEMORY_SCOPE_AGENT);
    if (r == TEAM - 1) {
      int exp0 = 0;
      __hip_atomic_compare_exchange_strong(winner, &exp0, xcc + 1,
          __ATOMIC_RELAXED, __ATOMIC_RELAXED, __HIP_MEMORY_SCOPE_AGENT);
    }
    int wt;
    do {
      wt = __hip_atomic_load(winner, __ATOMIC_RELAXED, __HIP_MEMORY_SCOPE_AGENT);
    } while (wt == 0);   // terminates: 256 blocks @1/CU are all resident, so
                         // every XCD reaches TEAM tickets -> CAS fires
    s_rank = (xcc == wt - 1 && r < TEAM) ? r : -1;
  }
  __syncthreads();
  const int rank = s_rank;
  if (rank < 0) return;  // 224 non-elected blocks exit, freeing their CUs

  // ---- W fragments: wave wv -> cols [rank*64 + (wv&1)*32, +32), 2 col-tiles
  const int co  = (wv & 1) * 32;
  const int rh  = (wv >> 1) * 64;            // this wave's 64 output rows
  const int g   = l15 & 3;                   // gate id (same for both ct)
  const float* Wg = (g == 0) ? Wi : (g == 1) ? Wf : (g == 2) ? Wo : Wh;
  short8 bfrag[2][24];
#pragma unroll
  for (int ct = 0; ct < 2; ++ct) {
    const int jcol = rank * 16 + (wv & 1) * 8 + ct * 4 + (l15 >> 2);
#pragma unroll
    for (int kt = 0; kt < 24; ++kt) {
      union { short8 s; unsigned short us[8]; } cv;
#pragma unroll
      for (int e = 0; e < 8; ++e) {
        int k = kt * 32 + l4 * 8 + e;
        cv.us[e] = f2bf(Wg[(size_t)k * HIDN + jcol]);
      }
      bfrag[ct][kt] = cv.s;
    }
  }

  int   jgl[2];
  float bI[2], bF[2], bO[2], bH[2];
#pragma unroll
  for (int ct = 0; ct < 2; ++ct) {
    jgl[ct] = rank * 16 + (wv & 1) * 8 + ct * 4 + l4;
    bI[ct] = bi[jgl[ct]]; bF[ct] = bf_[jgl[ct]];
    bO[ct] = bo[jgl[ct]]; bH[ct] = bh[jgl[ct]];
  }
  float c[4][2];
#pragma unroll
  for (int rt = 0; rt < 4; ++rt) { c[rt][0] = 0.f; c[rt][1] = 0.f; }

  unsigned short* hcur = hb;                       // zeroed by host memset: h_0 = 0
  unsigned short* hnxt = hb + (size_t)NB * HIDN;

  // ---- acc preloaded with x-GEMM for t=0 ----
  floatx4 acc[4][2];
#pragma unroll
  for (int rt = 0; rt < 4; ++rt) {
    int n = rh + rt * 16 + l15;
    short8 xq[8];
    if (USE_XE) {
      const unsigned short* xr = xe + (size_t)n * EMB + l4 * 8;
#pragma unroll
      for (int kt = 0; kt < 8; ++kt) xq[kt] = *(const short8*)(xr + kt * 32);
    } else {
      int idx = X[(size_t)n * LSEQ + 0];
      const float* er = E + (size_t)idx * EMB + l4 * 8;
#pragma unroll
      for (int kt = 0; kt < 8; ++kt) {
        float4 u = *(const float4*)(er + kt * 32);
        float4 v = *(const float4*)(er + kt * 32 + 4);
        xq[kt] = pack8(u, v);
      }
    }
    acc[rt][0] = floatx4{0.f, 0.f, 0.f, 0.f};
    acc[rt][1] = floatx4{0.f, 0.f, 0.f, 0.f};
#pragma unroll
    for (int kt = 0; kt < 8; ++kt) {
      acc[rt][0] = __builtin_amdgcn_mfma_f32_16x16x32_bf16(bfrag[0][16 + kt], xq[kt], acc[rt][0], 0, 0, 0);
      acc[rt][1] = __builtin_amdgcn_mfma_f32_16x16x32_bf16(bfrag[1][16 + kt], xq[kt], acc[rt][1], 0, 0, 0);
    }
  }

  const int swz = (l15 & 7) << 4;            // read swizzle: (row)&7 == l15&7

  for (int t = 0; t < LSEQ; ++t) {
    // ---- stage h(t): wave pulls rows [wv*32, +32) via sc0 (local-L2) loads,
    //      one fully-coalesced 1KB row per instruction, all 32 in flight ----
    short8 pv[32];
    const char* hrow = (const char*)hcur + (size_t)(wv * 32) * 1024 + lane * 16;
#pragma unroll
    for (int cc = 0; cc < 32; ++cc)
      pv[cc] = ld16_sc0(hrow + cc * 1024);
    asm volatile("s_waitcnt vmcnt(0)" ::: "memory");
#pragma unroll
    for (int cc = 0; cc < 32; ++cc) {
      int row = wv * 32 + cc;
      *(short8*)(smem + ((row * 1024 + lane * 16) ^ ((cc & 7) << 4))) = pv[cc];
    }
    __syncthreads();                         // A: tile staged

    // ---- h-GEMM: 16 kt x 4 row-tiles x 2 col-tiles ----
#pragma unroll
    for (int kt = 0; kt < 16; ++kt) {
      short8 hq[4];
#pragma unroll
      for (int rt = 0; rt < 4; ++rt) {
        int n = rh + rt * 16 + l15;
        hq[rt] = *(const short8*)(smem + ((n * 1024 + kt * 64 + l4 * 16) ^ swz));
      }
#pragma unroll
      for (int rt = 0; rt < 4; ++rt) {
        acc[rt][0] = __builtin_amdgcn_mfma_f32_16x16x32_bf16(bfrag[0][kt], hq[rt], acc[rt][0], 0, 0, 0);
        acc[rt][1] = __builtin_amdgcn_mfma_f32_16x16x32_bf16(bfrag[1][kt], hq[rt], acc[rt][1], 0, 0, 0);
      }
    }

    // ---- gates + h(t+1) store: lane -> h[n = rh+rt*16+l15][j = jgl[ct]] ----
#pragma unroll
    for (int rt = 0; rt < 4; ++rt) {
#pragma unroll
      for (int ct = 0; ct < 2; ++ct) {
        floatx4 z = acc[rt][ct];
        float ig = sigmoid_f(z[0] + bI[ct]);
        float fg = sigmoid_f(z[1] + bF[ct]);
        float og = sigmoid_f(z[2] + bO[ct]);
        float gg = tanh_f(z[3] + bH[ct]);
        c[rt][ct] = fg * c[rt][ct] + ig * gg;
        float hv = og * tanh_f(c[rt][ct]);

        int n = rh + rt * 16 + l15;
        unsigned w  = (unsigned)f2bf(hv);
        unsigned wp = (unsigned)__builtin_amdgcn_ds_swizzle((int)w, 0x401F); // xor 16
        if ((l4 & 1) == 0) {   // pack (j, j+1): partner lane^16 has l4+1
          unsigned val = w | (wp << 16);
          unsigned* p = (unsigned*)(hnxt + (size_t)n * HIDN + jgl[ct]);
          __hip_atomic_store(p, val, __ATOMIC_RELAXED, __HIP_MEMORY_SCOPE_WORKGROUP);
        }
        if (t == LSEQ - 1)
          out[(size_t)n * HIDN + jgl[ct]] = hv;
      }
    }

    if (t == LSEQ - 1) break;

    { unsigned short* tmp = hcur; hcur = hnxt; hnxt = tmp; }

    const int gen = t + 1;
    // B: drains h stores to the XCD L2 (vmcnt 0) + orders this step's LDS
    // reads before next step's ds_writes. Flag goes out after.
    __syncthreads();
    if (tid == 0)
      __hip_atomic_store(&arrive[rank], gen, __ATOMIC_RELAXED,
                         __HIP_MEMORY_SCOPE_WORKGROUP);

    // ---- off-chain: x-GEMM for t+1 while teammates arrive ----
#pragma unroll
    for (int rt = 0; rt < 4; ++rt) {
      int n = rh + rt * 16 + l15;
      short8 xq[8];
      if (USE_XE) {
        const unsigned short* xr = xe + ((size_t)(t + 1) * NB + n) * EMB + l4 * 8;
#pragma unroll
        for (int kt = 0; kt < 8; ++kt) xq[kt] = *(const short8*)(xr + kt * 32);
      } else {
        int idx = X[(size_t)n * LSEQ + t + 1];
        const float* er = E + (size_t)idx * EMB + l4 * 8;
#pragma unroll
        for (int kt = 0; kt < 8; ++kt) {
          float4 u = *(const float4*)(er + kt * 32);
          float4 v = *(const float4*)(er + kt * 32 + 4);
          xq[kt] = pack8(u, v);
        }
      }
      acc[rt][0] = floatx4{0.f, 0.f, 0.f, 0.f};
      acc[rt][1] = floatx4{0.f, 0.f, 0.f, 0.f};
#pragma unroll
      for (int kt = 0; kt < 8; ++kt) {
        acc[rt][0] = __builtin_amdgcn_mfma_f32_16x16x32_bf16(bfrag[0][16 + kt], xq[kt], acc[rt][0], 0, 0, 0);
        acc[rt][1] = __builtin_amdgcn_mfma_f32_16x16x32_bf16(bfrag[1][16 + kt], xq[kt], acc[rt][1], 0, 0, 0);
      }
    }

    // ---- poll: 32 flags in one L2 line; lane spins on flag lane&31 (sc0) ----
    {
      const int* fp = &arrive[lane & 31];
      int va;
      do { va = ld_flag_sc0(fp); } while (va < gen);
    }
    __atomic_signal_fence(__ATOMIC_ACQUIRE);  // compiler barrier only
  }
}

// ws layout: [0, 8192) control (flags/ticket/winner), [8192, +262144) h double
// buffer, then (optional, if ws_size permits) xe bf16 time-major (33.5 MB).
extern "C" void kernel_launch(void* const* d_in, const int* in_sizes, int n_in,
                              void* d_out, int out_size, void* d_ws, size_t ws_size,
                              hipStream_t stream) {
  const int*   X  = (const int*)d_in[0];
  const float* E  = (const float*)d_in[1];
  const float* Wi = (const float*)d_in[2];
  const float* bi = (const float*)d_in[3];
  const float* Wf = (const float*)d_in[4];
  const float* bf = (const float*)d_in[5];
  const float* Wo = (const float*)d_in[6];
  const float* bo = (const float*)d_in[7];
  const float* Wh = (const float*)d_in[8];
  const float* bh = (const float*)d_in[9];
  float* out = (float*)d_out;

  char* ws = (char*)d_ws;
  int* ctrl = (int*)ws;
  unsigned short* hb = (unsigned short*)(ws + 8192);
  const size_t xe_off = 8192 + 2 * (size_t)NB * HIDN * sizeof(unsigned short);
  const size_t xe_bytes = (size_t)LSEQ * NB * EMB * sizeof(unsigned short);
  const bool use_xe = ws_size >= xe_off + xe_bytes;
  unsigned short* xe = use_xe ? (unsigned short*)(ws + xe_off) : nullptr;

  hipMemsetAsync(ws, 0, xe_off, stream);  // zero flags/ticket/winner + h_0

  if (use_xe)
    prep_x_kernel<<<dim3(LSEQ, NB), dim3(64), 0, stream>>>(X, E, xe);

  if (use_xe)
    lstm_main<true><<<dim3(GRID_ALL), dim3(256), 0, stream>>>(
        X, E, xe, Wi, bi, Wf, bf, Wo, bo, Wh, bh, out, hb, ctrl);
  else
    lstm_main<false><<<dim3(GRID_ALL), dim3(256), 0, stream>>>(
        X, E, xe, Wi, bi, Wf, bf, Wo, bo, Wh, bh, out, hb, ctrl);
}